// Round 1
// baseline (309.814 us; speedup 1.0000x reference)
//
#include <hip/hip_runtime.h>

typedef unsigned short u16;
typedef unsigned int u32;
typedef __bf16 bf16x8 __attribute__((ext_vector_type(8)));
typedef float f32x4 __attribute__((ext_vector_type(4)));

#define NTOK 8192
#define DM 512
#define NH 8
#define DKH 64
#define DFF 256

__device__ __forceinline__ float bf2f(u16 u) { return __uint_as_float(((u32)u) << 16); }
__device__ __forceinline__ u16 f2bf(float f) {
    u32 u = __float_as_uint(f);
    u32 r = u + 0x7fffu + ((u >> 16) & 1u);
    return (u16)(r >> 16);
}
__device__ __forceinline__ u32 pack2(float a, float b) {
    return (u32)f2bf(a) | ((u32)f2bf(b) << 16);
}

// ---------------- transpose + fp32->bf16 cast: src[R][C] f32 -> dst[C][R] bf16
__global__ __launch_bounds__(256) void transpose_cast(const float* __restrict__ src,
                                                      u16* __restrict__ dst, int R, int C) {
    __shared__ float tile[32][33];
    int c0 = blockIdx.x * 32, r0 = blockIdx.y * 32;
    int tx = threadIdx.x, ty = threadIdx.y;  // 32 x 8
#pragma unroll
    for (int i = 0; i < 4; ++i)
        tile[ty + i * 8][tx] = src[(size_t)(r0 + ty + i * 8) * C + c0 + tx];
    __syncthreads();
#pragma unroll
    for (int i = 0; i < 4; ++i)
        dst[(size_t)(c0 + ty + i * 8) * R + r0 + tx] = f2bf(tile[tx][ty + i * 8]);
}

__global__ __launch_bounds__(256) void concat3(const float* __restrict__ a,
                                               const float* __restrict__ b,
                                               const float* __restrict__ c,
                                               float* __restrict__ out) {
    int i = blockIdx.x * 256 + threadIdx.x;
    if (i < 512) out[i] = a[i];
    else if (i < 1024) out[i] = b[i - 512];
    else if (i < 1536) out[i] = c[i - 1024];
}

// ---------------- Norm: alpha*(x-mean)/(std+eps)+beta, std ddof=1, out bf16
__global__ __launch_bounds__(128) void norm_cast_kernel(const float* __restrict__ x,
                                                        const float* __restrict__ alpha,
                                                        const float* __restrict__ beta,
                                                        u16* __restrict__ out) {
    int row = blockIdx.x;
    int tid = threadIdx.x;  // 128 threads, 4 floats each
    float4 v = ((const float4*)(x + (size_t)row * DM))[tid];
    float s = v.x + v.y + v.z + v.w;
#pragma unroll
    for (int m = 32; m; m >>= 1) s += __shfl_xor(s, m);
    __shared__ float red[2], red2[2];
    if ((tid & 63) == 0) red[tid >> 6] = s;
    __syncthreads();
    float mean = (red[0] + red[1]) * (1.f / 512.f);
    float dx = v.x - mean, dy = v.y - mean, dz = v.z - mean, dw = v.w - mean;
    float ss = dx * dx + dy * dy + dz * dz + dw * dw;
#pragma unroll
    for (int m = 32; m; m >>= 1) ss += __shfl_xor(ss, m);
    if ((tid & 63) == 0) red2[tid >> 6] = ss;
    __syncthreads();
    float var = (red2[0] + red2[1]) * (1.f / 511.f);
    float rs = 1.f / (sqrtf(var) + 1e-6f);
    float4 a = ((const float4*)alpha)[tid];
    float4 b = ((const float4*)beta)[tid];
    uint2 o;
    o.x = pack2(a.x * dx * rs + b.x, a.y * dy * rs + b.y);
    o.y = pack2(a.z * dz * rs + b.z, a.w * dw * rs + b.w);
    ((uint2*)(out + (size_t)row * DM))[tid] = o;
}

// ---------------- bf16 MFMA GEMM: out = A[M][K] @ Bt[N][K]^T, fused epilogue
#define LDST 56  // LDS row stride in bf16 elems (112B: 16B-aligned, conflict-light)

template <bool BIAS, bool RES, bool RELU, bool OUT_BF16>
__global__ __launch_bounds__(256) void gemm_bt(const u16* __restrict__ A,
                                               const u16* __restrict__ Bt,
                                               const float* __restrict__ bias,
                                               const float* __restrict__ res,
                                               float* __restrict__ outf,
                                               u16* __restrict__ outb,
                                               int M, int N, int K, float scale) {
    __shared__ uint4 As4[128 * LDST / 8];
    __shared__ uint4 Bs4[128 * LDST / 8];
    u16* As = (u16*)As4;
    u16* Bs = (u16*)Bs4;
    const int tid = threadIdx.x;
    const int lane = tid & 63;
    const int wave = tid >> 6;
    const int wr = wave >> 1, wc = wave & 1;
    const int tm = blockIdx.y * 128, tn = blockIdx.x * 128;
    const int l15 = lane & 15, lg = lane >> 4;

    f32x4 acc[4][4] = {};

    for (int k0 = 0; k0 < K; k0 += 32) {
#pragma unroll
        for (int j = 0; j < 2; ++j) {
            int idx = tid + j * 256;
            int r = idx >> 2, cb = (idx & 3) << 3;
            uint4 va = *(const uint4*)(A + (size_t)(tm + r) * K + k0 + cb);
            uint4 vb = *(const uint4*)(Bt + (size_t)(tn + r) * K + k0 + cb);
            *(uint4*)(As + r * LDST + cb) = va;
            *(uint4*)(Bs + r * LDST + cb) = vb;
        }
        __syncthreads();
        bf16x8 af[4], bfr[4];
#pragma unroll
        for (int i = 0; i < 4; ++i) {
            af[i] = *(const bf16x8*)(As + (wr * 64 + i * 16 + l15) * LDST + lg * 8);
            bfr[i] = *(const bf16x8*)(Bs + (wc * 64 + i * 16 + l15) * LDST + lg * 8);
        }
#pragma unroll
        for (int mi = 0; mi < 4; ++mi)
#pragma unroll
            for (int ni = 0; ni < 4; ++ni)
                acc[mi][ni] = __builtin_amdgcn_mfma_f32_16x16x32_bf16(af[mi], bfr[ni],
                                                                     acc[mi][ni], 0, 0, 0);
        __syncthreads();
    }

#pragma unroll
    for (int mi = 0; mi < 4; ++mi) {
#pragma unroll
        for (int ni = 0; ni < 4; ++ni) {
            int col = tn + wc * 64 + ni * 16 + l15;
            int row0 = tm + wr * 64 + mi * 16 + lg * 4;
            float b = BIAS ? bias[col] : 0.f;
#pragma unroll
            for (int r = 0; r < 4; ++r) {
                size_t off = (size_t)(row0 + r) * N + col;
                float v = acc[mi][ni][r] * scale + b;
                if (RES) v += res[off];
                if (RELU) v = fmaxf(v, 0.f);
                if (OUT_BF16) outb[off] = f2bf(v);
                else outf[off] = v;
            }
        }
    }
}

// ---------------- query softmax over head channels (64), one wave per (row,head)
__global__ __launch_bounds__(256) void qsm_kernel(const u16* __restrict__ kqv,
                                                  u16* __restrict__ qsm) {
    int rh = blockIdx.x * 4 + (threadIdx.x >> 6);
    int lane = threadIdx.x & 63;
    int row = rh >> 3, head = rh & 7;
    float v = bf2f(kqv[(size_t)row * 1536 + 512 + head * 64 + lane]);
    float m = v;
#pragma unroll
    for (int s = 32; s; s >>= 1) m = fmaxf(m, __shfl_xor(m, s));
    float e = __expf(v - m);
    float sum = e;
#pragma unroll
    for (int s = 32; s; s >>= 1) sum += __shfl_xor(sum, s);
    qsm[(size_t)row * DM + head * 64 + lane] = f2bf(e / sum);
}

// ---------------- key softmax over tokens (axis 0): hierarchical
__global__ __launch_bounds__(256) void ksm_part(const u16* __restrict__ kqv,
                                                float* __restrict__ pmax,
                                                float* __restrict__ psum) {
    int b = blockIdx.x;  // 64 blocks x 128 rows
    int t = threadIdx.x;
    int c = t * 2;
    float m0 = -1e30f, m1 = -1e30f, s0 = 0.f, s1 = 0.f;
    int r0 = b * 128;
    for (int r = r0; r < r0 + 128; ++r) {
        u32 u = *(const u32*)(kqv + (size_t)r * 1536 + c);
        float v0 = bf2f((u16)u), v1 = bf2f((u16)(u >> 16));
        float nm0 = fmaxf(m0, v0);
        s0 = s0 * __expf(m0 - nm0) + __expf(v0 - nm0);
        m0 = nm0;
        float nm1 = fmaxf(m1, v1);
        s1 = s1 * __expf(m1 - nm1) + __expf(v1 - nm1);
        m1 = nm1;
    }
    pmax[b * 512 + c] = m0;
    pmax[b * 512 + c + 1] = m1;
    psum[b * 512 + c] = s0;
    psum[b * 512 + c + 1] = s1;
}

__global__ __launch_bounds__(512) void ksm_reduce(const float* __restrict__ pmax,
                                                  const float* __restrict__ psum,
                                                  float* __restrict__ colmax,
                                                  float* __restrict__ colrcp) {
    int c = threadIdx.x;
    float m = -1e30f, s = 0.f;
    for (int b = 0; b < 64; ++b) {
        float pm = pmax[b * 512 + c], ps = psum[b * 512 + c];
        float nm = fmaxf(m, pm);
        s = s * __expf(m - nm) + ps * __expf(pm - nm);
        m = nm;
    }
    colmax[c] = m;
    colrcp[c] = 1.f / s;
}

__global__ __launch_bounds__(256) void ksm_write(const u16* __restrict__ kqv,
                                                 const float* __restrict__ colmax,
                                                 const float* __restrict__ colrcp,
                                                 u16* __restrict__ ksm) {
    int idx = blockIdx.x * 256 + threadIdx.x;  // 8192*256 pairs
    int row = idx >> 8, cp = idx & 255;
    int c = cp * 2;
    u32 u = *(const u32*)(kqv + (size_t)row * 1536 + c);
    float v0 = bf2f((u16)u), v1 = bf2f((u16)(u >> 16));
    float o0 = __expf(v0 - colmax[c]) * colrcp[c];
    float o1 = __expf(v1 - colmax[c + 1]) * colrcp[c + 1];
    *(u32*)(ksm + (size_t)row * DM + c) = pack2(o0, o1);
}

// ---------------- context partials: ctx[h][k][v] = sum_n ksm[n][h,k]*values[n][h,v]
__global__ __launch_bounds__(256) void ctx_part_kernel(const u16* __restrict__ ksm,
                                                       const u16* __restrict__ kqv,
                                                       float* __restrict__ part) {
    int chunk = blockIdx.x;  // 16 chunks x 512 tokens
    int h = blockIdx.y;
    __shared__ float kt[64 * 64], vt[64 * 64];
    int t = threadIdx.x;
    int kg = t >> 4, vg = t & 15;
    float acc[4][4] = {};
    for (int sub = 0; sub < 8; ++sub) {
        int tok0 = chunk * 512 + sub * 64;
        __syncthreads();
#pragma unroll
        for (int j = 0; j < 16; ++j) {
            int e = t + j * 256;
            int tok = e >> 6, ch = e & 63;
            kt[e] = bf2f(ksm[(size_t)(tok0 + tok) * DM + h * 64 + ch]);
            vt[e] = bf2f(kqv[(size_t)(tok0 + tok) * 1536 + 1024 + h * 64 + ch]);
        }
        __syncthreads();
        for (int n = 0; n < 64; ++n) {
            float4 kv = *(float4*)&kt[n * 64 + kg * 4];
            float4 vv = *(float4*)&vt[n * 64 + vg * 4];
            float ka[4] = {kv.x, kv.y, kv.z, kv.w};
            float va[4] = {vv.x, vv.y, vv.z, vv.w};
#pragma unroll
            for (int i = 0; i < 4; ++i)
#pragma unroll
                for (int j = 0; j < 4; ++j) acc[i][j] += ka[i] * va[j];
        }
    }
    float* dst = part + (size_t)(chunk * 8 + h) * 4096;
#pragma unroll
    for (int i = 0; i < 4; ++i)
#pragma unroll
        for (int j = 0; j < 4; ++j) dst[(kg * 4 + i) * 64 + vg * 4 + j] = acc[i][j];
}

__global__ __launch_bounds__(256) void ctx_reduce(const float* __restrict__ part,
                                                  float* __restrict__ ctx) {
    int idx = blockIdx.x * 256 + threadIdx.x;  // 32768 outputs
    int h = idx >> 12, o = idx & 4095;
    float s = 0.f;
    for (int c = 0; c < 16; ++c) s += part[(size_t)(c * 8 + h) * 4096 + o];
    ctx[(size_t)h * 4096 + o] = s;
}

// ---------------- attended[n][h*64+v] = sum_k qsm[n][h,k] * ctx[h][k][v]
__global__ __launch_bounds__(256) void attended_kernel(const u16* __restrict__ qsm,
                                                       const float* __restrict__ ctx,
                                                       u16* __restrict__ att) {
    int h = blockIdx.y;
    int r0 = blockIdx.x * 128;
    __shared__ float cs[64 * 64];
    __shared__ float qs[128 * 65];
    int t = threadIdx.x;
#pragma unroll
    for (int j = 0; j < 16; ++j) cs[t + j * 256] = ctx[(size_t)h * 4096 + t + j * 256];
#pragma unroll
    for (int j = 0; j < 32; ++j) {
        int e = t + j * 256;
        int r = e >> 6, c = e & 63;
        qs[r * 65 + c] = bf2f(qsm[(size_t)(r0 + r) * DM + h * 64 + c]);
    }
    __syncthreads();
    int rg = t >> 3;        // 32 groups * 4 rows
    int cg = t & 7;         // 8 groups * 8 cols
    float acc[4][8] = {};
    for (int k = 0; k < 64; ++k) {
        float q0 = qs[(rg * 4 + 0) * 65 + k];
        float q1 = qs[(rg * 4 + 1) * 65 + k];
        float q2 = qs[(rg * 4 + 2) * 65 + k];
        float q3 = qs[(rg * 4 + 3) * 65 + k];
        float4 c0 = *(float4*)&cs[k * 64 + cg * 8];
        float4 c1 = *(float4*)&cs[k * 64 + cg * 8 + 4];
        float cv[8] = {c0.x, c0.y, c0.z, c0.w, c1.x, c1.y, c1.z, c1.w};
        float qv[4] = {q0, q1, q2, q3};
#pragma unroll
        for (int i = 0; i < 4; ++i)
#pragma unroll
            for (int j = 0; j < 8; ++j) acc[i][j] += qv[i] * cv[j];
    }
#pragma unroll
    for (int i = 0; i < 4; ++i) {
        u16* dst = att + (size_t)(r0 + rg * 4 + i) * DM + h * 64 + cg * 8;
        ((u32*)dst)[0] = pack2(acc[i][0], acc[i][1]);
        ((u32*)dst)[1] = pack2(acc[i][2], acc[i][3]);
        ((u32*)dst)[2] = pack2(acc[i][4], acc[i][5]);
        ((u32*)dst)[3] = pack2(acc[i][6], acc[i][7]);
    }
}

extern "C" void kernel_launch(void* const* d_in, const int* in_sizes, int n_in,
                              void* d_out, int out_size, void* d_ws, size_t ws_size,
                              hipStream_t stream) {
    const float* x = (const float*)d_in[0];
    const float* Wk = (const float*)d_in[1];
    const float* bk = (const float*)d_in[2];
    const float* Wq = (const float*)d_in[3];
    const float* bq = (const float*)d_in[4];
    const float* Wv = (const float*)d_in[5];
    const float* bv = (const float*)d_in[6];
    const float* Wr = (const float*)d_in[7];
    const float* br = (const float*)d_in[8];
    const float* alpha1 = (const float*)d_in[9];
    const float* beta1 = (const float*)d_in[10];
    const float* alpha2 = (const float*)d_in[11];
    const float* beta2 = (const float*)d_in[12];
    const float* W1 = (const float*)d_in[13];
    const float* b1 = (const float*)d_in[14];
    const float* W2 = (const float*)d_in[15];
    const float* b2 = (const float*)d_in[16];

    char* ws = (char*)d_ws;
    u16* x2 = (u16*)(ws + 0);                    // 8 MB (reused for x2b after attn)
    u16* wqkvT = (u16*)(ws + 8388608);           // 1.5 MB
    u16* wrT = (u16*)(ws + 9961472);             // 0.5 MB
    u16* w1T = (u16*)(ws + 10485760);            // 256 KB
    u16* w2T = (u16*)(ws + 10747904);            // 256 KB
    float* bkqv = (float*)(ws + 11010048);       // 6 KB
    u16* kqv = (u16*)(ws + 11016192);            // 24 MB (reused for ff hidden)
    u16* qsm = (u16*)(ws + 36182016);            // 8 MB
    u16* ksm = (u16*)(ws + 44570624);            // 8 MB
    float* pmax = (float*)(ws + 52959232);       // 128 KB
    float* psum = (float*)(ws + 53090304);       // 128 KB
    float* colmax = (float*)(ws + 53221376);     // 2 KB
    float* colrcp = (float*)(ws + 53223424);     // 2 KB
    float* ctxp = (float*)(ws + 53225472);       // 2 MB
    float* ctx = (float*)(ws + 55322624);        // 128 KB
    u16* att = (u16*)(ws + 55453696);            // 8 MB
    float* xmid = (float*)(ws + 63842304);       // 16 MB
    u16* hbuf = kqv;                             // ff hidden reuses kqv

    float* out_x = (float*)d_out;
    float* out_scores = (float*)d_out + (size_t)NTOK * DM;

    dim3 tb(32, 8);
    transpose_cast<<<dim3(16, 16), tb, 0, stream>>>(Wk, wqkvT, 512, 512);
    transpose_cast<<<dim3(16, 16), tb, 0, stream>>>(Wq, wqkvT + 512 * 512, 512, 512);
    transpose_cast<<<dim3(16, 16), tb, 0, stream>>>(Wv, wqkvT + 1024 * 512, 512, 512);
    transpose_cast<<<dim3(16, 16), tb, 0, stream>>>(Wr, wrT, 512, 512);
    transpose_cast<<<dim3(8, 16), tb, 0, stream>>>(W1, w1T, 512, 256);
    transpose_cast<<<dim3(16, 8), tb, 0, stream>>>(W2, w2T, 256, 512);
    concat3<<<6, 256, 0, stream>>>(bk, bq, bv, bkqv);

    norm_cast_kernel<<<NTOK, 128, 0, stream>>>(x, alpha1, beta1, x2);

    // fused QKV: [8192,512] @ [512,1536] -> bf16
    gemm_bt<true, false, false, true><<<dim3(12, 64), 256, 0, stream>>>(
        x2, wqkvT, bkqv, nullptr, nullptr, kqv, NTOK, 1536, 512, 1.f);

    qsm_kernel<<<NTOK * NH / 4, 256, 0, stream>>>(kqv, qsm);
    ksm_part<<<64, 256, 0, stream>>>(kqv, pmax, psum);
    ksm_reduce<<<1, 512, 0, stream>>>(pmax, psum, colmax, colrcp);
    ksm_write<<<NTOK, 256, 0, stream>>>(kqv, colmax, colrcp, ksm);

    ctx_part_kernel<<<dim3(16, 8), 256, 0, stream>>>(ksm, kqv, ctxp);
    ctx_reduce<<<128, 256, 0, stream>>>(ctxp, ctx);
    attended_kernel<<<dim3(64, 8), 256, 0, stream>>>(qsm, ctx, att);

    // attn = attended @ Wr + br; x_mid = x + attn
    gemm_bt<true, true, false, false><<<dim3(4, 64), 256, 0, stream>>>(
        att, wrT, br, x, xmid, nullptr, NTOK, 512, 512, 1.f);

    norm_cast_kernel<<<NTOK, 128, 0, stream>>>(xmid, alpha2, beta2, x2);

    // ff1: relu(x2b @ W1 + b1) -> bf16
    gemm_bt<true, false, true, true><<<dim3(2, 64), 256, 0, stream>>>(
        x2, w1T, b1, nullptr, nullptr, hbuf, NTOK, 256, 512, 1.f);
    // ff2: h @ W2 + b2 + x_mid -> out x
    gemm_bt<true, true, false, false><<<dim3(4, 64), 256, 0, stream>>>(
        hbuf, w2T, b2, xmid, out_x, nullptr, NTOK, 512, 256, 1.f);

    // scores = (qsm @ ksm^T) / 8 -> fp32 [8192][8192]
    gemm_bt<false, false, false, false><<<dim3(64, 64), 256, 0, stream>>>(
        qsm, ksm, nullptr, nullptr, out_scores, nullptr, NTOK, NTOK, 512, 0.125f);
}